// Round 1
// baseline (368.689 us; speedup 1.0000x reference)
//
#include <hip/hip_runtime.h>
#include <hip/hip_bf16.h>
#include <math.h>

// Problem constants
#define BATCH 1024
#define FEAT  2048
#define NCLS  11003
#define NPAD  11008      // 86 * 128
#define NT1   86         // N tiles for gemm1
#define NPART (NT1 * 2)  // psum partials per row (2 waves in N per tile)
#define M1    2048       // stacked [v; t]
#define C_SCALE  28.0f
#define C_ALPHA  0.6f
#define C_BETA   0.4f
#define C_SPOS   10.0f
#define C_SNEG   40.0f
#define XSCALE   16.0f              // Xn pre-scale into e4m3 normal range
#define SCL1     (C_SCALE / XSCALE) // logit = SCL1 * rcol * acc
#define SIMSCL   (1.0f / (XSCALE * XSCALE))
#define SCALE1   0x7F7F7F7F         // packed E8M0 = 1.0 in every byte

typedef float floatx4 __attribute__((ext_vector_type(4)));
typedef float f32x16  __attribute__((ext_vector_type(16)));
typedef int   v8i     __attribute__((ext_vector_type(8)));
typedef unsigned char u8;

// ---- workspace layout (bytes) ----
#define O_ALIGN  ((size_t)0)         // f32 align_sum
#define O_INST   ((size_t)64)        // f32 instance-CE sum
#define O_FIN    ((size_t)128)       // int fin counter (merge blocks)
#define O_COLSQ  ((size_t)256)       // NPAD f32  (ends 44288)
#define O_XN     ((size_t)44288)     // 2048*2048 fp8 (normalized [v;t], x16)
#define O_WT     ((size_t)4238592)   // NPAD*2048 fp8 (W^T, raw values)
#define O_PSUM   ((size_t)26782976)  // 2048*NPART f32
#define O_LL     ((size_t)28192000)  // 2048 f32 label logits
// zeroed prefix: [0, O_XN)

#define PREP_WBLOCKS (43 * 32)       // 1376: 256-class x 64-feature tiles
#define PREP_TOTAL   (PREP_WBLOCKS + M1)

__device__ inline float softplusf(float x) {
    return (x > 20.f) ? x : log1pf(expf(x));
}

// async 16B global -> LDS (wave-uniform base + lane*16; layout is lane-linear)
__device__ inline void gll16(const void* g, void* l) {
    __builtin_amdgcn_global_load_lds(
        (const __attribute__((address_space(1))) unsigned int*)g,
        (__attribute__((address_space(3))) unsigned int*)l, 16, 0, 0);
}

__device__ inline unsigned int pack4_fp8(float a, float b, float c, float d) {
    unsigned int p = __builtin_amdgcn_cvt_pk_fp8_f32(a, b, 0, false);
    p = __builtin_amdgcn_cvt_pk_fp8_f32(c, d, p, true);
    return p;  // bytes: a,b,c,d
}

// XOR swizzle on 16B-chunk index (self-inverse) — measured 0 bank conflicts (R5)
__device__ inline int swz(int c) { return c ^ ((c >> 4) & 7); }

// ---------------- fused prep (unchanged) ----------------
__global__ __launch_bounds__(256) void k_prep(const float* __restrict__ vis,
                                              const float* __restrict__ txt,
                                              const float* __restrict__ W,
                                              u8* __restrict__ Xn,
                                              u8* __restrict__ WT,
                                              float* __restrict__ colsq) {
    __shared__ u8 tileT[1024 * 16];     // 16 KB: 1024 16B chunks (class x f-quad)
    __shared__ float cps[4][256];
    __shared__ float sb[256];
    int t = threadIdx.x;
    if (blockIdx.x < PREP_WBLOCKS) {
        int c0 = (blockIdx.x % 43) * 256, f0 = (blockIdx.x / 43) * 64;
        int w = t >> 6, l = t & 63;
        int cbase = c0 + 4 * l;              // this thread's 4 classes
        unsigned int chunks[4][4];           // [class j][row-quad q]
        float ssq0 = 0.f, ssq1 = 0.f, ssq2 = 0.f, ssq3 = 0.f;
        #pragma unroll
        for (int q = 0; q < 4; ++q) {
            float4 row[4];
            #pragma unroll
            for (int rr = 0; rr < 4; ++rr) {
                int f = f0 + w * 16 + q * 4 + rr;
                const float* p = W + (size_t)f * NCLS + cbase;
                float4 v;
                if (cbase + 3 < NCLS) {
                    __builtin_memcpy(&v, p, 16);   // HW unaligned global load
                } else {
                    v.x = (cbase + 0 < NCLS) ? p[0] : 0.f;
                    v.y = (cbase + 1 < NCLS) ? p[1] : 0.f;
                    v.z = (cbase + 2 < NCLS) ? p[2] : 0.f;
                    v.w = (cbase + 3 < NCLS) ? p[3] : 0.f;
                }
                row[rr] = v;
            }
            chunks[0][q] = pack4_fp8(row[0].x, row[1].x, row[2].x, row[3].x);
            chunks[1][q] = pack4_fp8(row[0].y, row[1].y, row[2].y, row[3].y);
            chunks[2][q] = pack4_fp8(row[0].z, row[1].z, row[2].z, row[3].z);
            chunks[3][q] = pack4_fp8(row[0].w, row[1].w, row[2].w, row[3].w);
            #pragma unroll
            for (int rr = 0; rr < 4; ++rr) {
                ssq0 += row[rr].x * row[rr].x;
                ssq1 += row[rr].y * row[rr].y;
                ssq2 += row[rr].z * row[rr].z;
                ssq3 += row[rr].w * row[rr].w;
            }
        }
        #pragma unroll
        for (int j = 0; j < 4; ++j) {
            int L = (4 * l + j) * 4 + w;     // logical chunk: class-local * 4 + f-quad
            int P = L ^ ((L >> 4) & 7);
            *(uint4*)(tileT + P * 16) =
                make_uint4(chunks[j][0], chunks[j][1], chunks[j][2], chunks[j][3]);
        }
        *(float4*)&cps[w][4 * l] = make_float4(ssq0, ssq1, ssq2, ssq3);
        __syncthreads();
        int c = c0 + t;
        uint4 och[4];
        #pragma unroll
        for (int w2 = 0; w2 < 4; ++w2) {
            int L = t * 4 + w2;
            int P = L ^ ((L >> 4) & 7);
            och[w2] = *(const uint4*)(tileT + P * 16);
        }
        uint4* dst = (uint4*)(WT + (size_t)c * FEAT + f0);
        dst[0] = och[0]; dst[1] = och[1]; dst[2] = och[2]; dst[3] = och[3];
        float s = cps[0][t] + cps[1][t] + cps[2][t] + cps[3][t];
        if (c < NCLS) atomicAdd(&colsq[c], s);
    } else {
        int r = blockIdx.x - PREP_WBLOCKS;
        const float* src = (r < BATCH) ? (vis + (size_t)r * FEAT)
                                       : (txt + (size_t)(r - BATCH) * FEAT);
        float4 x0 = ((const float4*)src)[t];
        float4 x1 = ((const float4*)src)[t + 256];
        float ss = x0.x*x0.x + x0.y*x0.y + x0.z*x0.z + x0.w*x0.w
                 + x1.x*x1.x + x1.y*x1.y + x1.z*x1.z + x1.w*x1.w;
        sb[t] = ss; __syncthreads();
        for (int s = 128; s > 0; s >>= 1) { if (t < s) sb[t] += sb[t + s]; __syncthreads(); }
        float rn = rsqrtf(sb[0]) * XSCALE;
        unsigned int* dst = (unsigned int*)(Xn + (size_t)r * FEAT);
        dst[t]       = pack4_fp8(x0.x*rn, x0.y*rn, x0.z*rn, x0.w*rn);
        dst[t + 256] = pack4_fp8(x1.x*rn, x1.y*rn, x1.z*rn, x1.w*rn);
    }
}

// ---------------- fused GEMM: lse tiles (y<86) + sim tiles (y>=86) ----------------
// 128x128 tile, BK=64 fp8, NOW double-buffered with depth-1 async prefetch:
// per K-step exactly one raw s_barrier + one vmcnt(0) (drains only the loads
// issued one full compute-phase earlier). Next tile's global_load_lds are
// issued immediately AFTER the barrier (overwrite target was last read one
// phase ago, behind that same barrier -> race-free).
// Wave tile 64x64 = 2x2 of 32x32. A frag: row=lane&31, K-half=lane>>5, 32 bytes.
// C/D: col=lane&31, row=(reg&3)+8*(reg>>2)+4*(lane>>5).
__global__ __launch_bounds__(256) void k_gemm(const u8* __restrict__ Xn,
                                              const u8* __restrict__ WT,
                                              const float* __restrict__ colsq,
                                              const int* __restrict__ labels,
                                              float* __restrict__ psum,
                                              float* __restrict__ ll,
                                              float* __restrict__ align_sum) {
    __shared__ u8 As[2 * 128 * 64], Bs[2 * 128 * 64];   // 16 KB + 16 KB (dbuf)
    f32x16 acc[2][2] = {};
    const int t = threadIdx.x;
    const bool is_sim = (blockIdx.y >= NT1);
    int m0, n0;
    const u8 *A, *B;
    if (!is_sim) {
        m0 = blockIdx.x * 128; n0 = blockIdx.y * 128;
        A = Xn; B = WT;
    } else {
        int s = (blockIdx.y - NT1) * 16 + blockIdx.x;   // 0..63
        m0 = (s >> 3) * 128; n0 = (s & 7) * 128;
        A = Xn; B = Xn + (size_t)BATCH * FEAT;
    }
    const int c0s = swz(t), c1s = swz(256 + t);
    const int ra0 = c0s >> 2, h0 = c0s & 3;
    const int ra1 = c1s >> 2, h1 = c1s & 3;
    const u8* Ag0 = A + (size_t)(m0 + ra0) * FEAT + h0 * 16;
    const u8* Ag1 = A + (size_t)(m0 + ra1) * FEAT + h1 * 16;
    const u8* Bg0 = B + (size_t)(n0 + ra0) * FEAT + h0 * 16;
    const u8* Bg1 = B + (size_t)(n0 + ra1) * FEAT + h1 * 16;
    u8* lA0 = As + t * 16;
    u8* lA1 = As + 4096 + t * 16;
    u8* lB0 = Bs + t * 16;
    u8* lB1 = Bs + 4096 + t * 16;

    const int wave = t >> 6, lane = t & 63;
    const int wm = wave >> 1, wn = wave & 1;
    const int l32 = lane & 31, kh = lane >> 5;
    // fragment read pointers (buffer 0 base): logical chunk = row*4 + kh*2 + c
    const uint4* Ard[2][2]; const uint4* Brd[2][2];
    #pragma unroll
    for (int i = 0; i < 2; ++i) {
        #pragma unroll
        for (int c = 0; c < 2; ++c) {
            Ard[i][c] = (const uint4*)(As + swz((wm*64 + i*32 + l32)*4 + kh*2 + c) * 16);
            Brd[i][c] = (const uint4*)(Bs + swz((wn*64 + i*32 + l32)*4 + kh*2 + c) * 16);
        }
    }

#define STAGE(buf) do { \
        gll16(Ag0, lA0 + (buf) * 8192); \
        gll16(Ag1, lA1 + (buf) * 8192); \
        gll16(Bg0, lB0 + (buf) * 8192); \
        gll16(Bg1, lB1 + (buf) * 8192); \
        Ag0 += 64; Ag1 += 64; Bg0 += 64; Bg1 += 64; \
    } while (0)

    // vmcnt(0) BEFORE issuing the next stage: drains only the one-phase-old
    // loads, so prefetch stays in flight across the barrier. Raw s_barrier
    // (no compiler-inserted full drain). sched_barrier pins ordering.
#define WAITB() do { \
        asm volatile("s_waitcnt vmcnt(0)" ::: "memory"); \
        __builtin_amdgcn_s_barrier(); \
        __builtin_amdgcn_sched_barrier(0); \
    } while (0)

#define COMPUTE(buf) do { \
        v8i a[2], b[2]; \
        _Pragma("unroll") \
        for (int i = 0; i < 2; ++i) { \
            ((uint4*)&a[i])[0] = *(const uint4*)((const u8*)Ard[i][0] + (buf) * 8192); \
            ((uint4*)&a[i])[1] = *(const uint4*)((const u8*)Ard[i][1] + (buf) * 8192); \
            ((uint4*)&b[i])[0] = *(const uint4*)((const u8*)Brd[i][0] + (buf) * 8192); \
            ((uint4*)&b[i])[1] = *(const uint4*)((const u8*)Brd[i][1] + (buf) * 8192); \
        } \
        _Pragma("unroll") \
        for (int i = 0; i < 2; ++i) \
            _Pragma("unroll") \
            for (int j = 0; j < 2; ++j) \
                acc[i][j] = __builtin_amdgcn_mfma_scale_f32_32x32x64_f8f6f4( \
                    a[i], b[j], acc[i][j], 0, 0, 0, SCALE1, 0, SCALE1); \
    } while (0)

    STAGE(0);                                   // prologue: tile 0 -> buf0
    for (int kt = 0; kt < FEAT / 64; kt += 2) {
        WAITB();                                // buf0 (tile kt) landed everywhere
        STAGE(1);                               // prefetch tile kt+1 -> buf1
        COMPUTE(0);
        WAITB();                                // buf1 landed; buf0 reads all done
        if (kt < FEAT / 64 - 2) STAGE(0);       // prefetch tile kt+2 -> buf0
        COMPUTE(1);
    }
#undef STAGE
#undef WAITB
#undef COMPUTE

    if (!is_sim) {
        // ---- LSE epilogue: fixed-max sum of exp(logit - 28) + label-logit scatter ----
        float rcol[2]; bool val[2]; int ncol[2];
        #pragma unroll
        for (int j = 0; j < 2; ++j) {
            ncol[j] = n0 + wn*64 + j*32 + l32;
            val[j] = (ncol[j] < NCLS);
            rcol[j] = val[j] ? (SCL1 * rsqrtf(colsq[ncol[j]])) : 0.f;
        }
        const int pidx = blockIdx.y * 2 + wn;
        #pragma unroll
        for (int i = 0; i < 2; ++i) {
            #pragma unroll
            for (int reg = 0; reg < 16; ++reg) {
                int m = m0 + wm*64 + i*32 + (reg & 3) + 8*(reg >> 2) + 4*kh;
                int lm = labels[m & (BATCH - 1)];
                float s = 0.f;
                #pragma unroll
                for (int j = 0; j < 2; ++j) {
                    if (val[j]) {
                        float v = acc[i][j][reg] * rcol[j];
                        if (ncol[j] == lm) ll[m] = v;
                        s += __expf(v - C_SCALE);
                    }
                }
                #pragma unroll
                for (int off = 1; off < 32; off <<= 1) s += __shfl_xor(s, off);
                if (l32 == 0) psum[(size_t)m * NPART + pidx] = s;
            }
        }
    } else {
        // ---- sim epilogue: masked softplus sum ----
        int ln[2];
        #pragma unroll
        for (int j = 0; j < 2; ++j) ln[j] = labels[n0 + wn*64 + j*32 + l32];
        float tot = 0.f;
        #pragma unroll
        for (int i = 0; i < 2; ++i) {
            #pragma unroll
            for (int reg = 0; reg < 16; ++reg) {
                int m = m0 + wm*64 + i*32 + (reg & 3) + 8*(reg >> 2) + 4*kh;
                int lm = labels[m];
                #pragma unroll
                for (int j = 0; j < 2; ++j) {
                    float s = acc[i][j][reg] * SIMSCL;
                    float arg = (lm == ln[j]) ? (-C_SPOS * (s - C_ALPHA))
                                              : ( C_SNEG * (s - C_BETA));
                    tot += softplusf(arg);
                }
            }
        }
        #pragma unroll
        for (int off = 1; off < 64; off <<= 1) tot += __shfl_xor(tot, off);
        if (lane == 0) atomicAdd(align_sum, tot);
    }
}

// ---------------- merge psum partials -> CE sum; last block writes out ----------------
__global__ __launch_bounds__(256) void k_merge(const float* __restrict__ psum,
                                               const float* __restrict__ ll,
                                               float* __restrict__ inst_sum,
                                               const float* __restrict__ align_sum,
                                               int* __restrict__ fin,
                                               float* __restrict__ out) {
    int r = blockIdx.x, t = threadIdx.x;
    float sm = (t < NPART) ? psum[(size_t)r * NPART + t] : 0.f;
    __shared__ float sb[256];
    sb[t] = sm; __syncthreads();
    for (int s = 128; s > 0; s >>= 1) { if (t < s) sb[t] += sb[t+s]; __syncthreads(); }
    if (t == 0) {
        atomicAdd(inst_sum, C_SCALE + logf(sb[0]) - ll[r]);
        __threadfence();
        if (atomicAdd(fin, 1) == M1 - 1) {          // last merge block
            __threadfence();
            float is = atomicAdd(inst_sum, 0.f);    // atomic read, device scope
            float as = atomicAdd((float*)align_sum, 0.f);
            out[0] = is / (float)BATCH;
            out[1] = as * 2.f / (float)BATCH;
        }
    }
}

extern "C" void kernel_launch(void* const* d_in, const int* in_sizes, int n_in,
                              void* d_out, int out_size, void* d_ws, size_t ws_size,
                              hipStream_t stream) {
    const float* vis    = (const float*)d_in[0];
    const float* txt    = (const float*)d_in[1];
    const int*   labels = (const int*)  d_in[2];
    const float* W      = (const float*)d_in[3];
    float* out = (float*)d_out;
    char*  ws  = (char*)d_ws;

    float* align_sum = (float*)(ws + O_ALIGN);
    float* inst_sum  = (float*)(ws + O_INST);
    int*   fin       = (int*)  (ws + O_FIN);
    float* colsq     = (float*)(ws + O_COLSQ);
    u8* Xn = (u8*)(ws + O_XN);
    u8* WT = (u8*)(ws + O_WT);
    float* psum = (float*)(ws + O_PSUM);
    float* ll   = (float*)(ws + O_LL);

    hipMemsetAsync(ws, 0, O_XN, stream);  // zero align/inst/fin/colsq

    k_prep <<<dim3(PREP_TOTAL), 256, 0, stream>>>(vis, txt, W, Xn, WT, colsq);
    k_gemm <<<dim3(M1 / 128, NT1 + 4), 256, 0, stream>>>(Xn, WT, colsq, labels,
                                                         psum, ll, align_sum);
    k_merge<<<dim3(M1), 256, 0, stream>>>(psum, ll, inst_sum, align_sum, fin, out);
}

// Round 2
// 368.129 us; speedup vs baseline: 1.0015x; 1.0015x over previous
//
#include <hip/hip_runtime.h>
#include <hip/hip_bf16.h>
#include <math.h>

// Problem constants
#define BATCH 1024
#define FEAT  2048
#define NCLS  11003
#define NPAD  11008      // 86 * 128
#define NT1   86         // N tiles for gemm1
#define NPART (NT1 * 2)  // psum partials per row (2 waves in N per tile)
#define M1    2048       // stacked [v; t]
#define C_SCALE  28.0f
#define C_ALPHA  0.6f
#define C_BETA   0.4f
#define C_SPOS   10.0f
#define C_SNEG   40.0f
#define XSCALE   16.0f              // Xn pre-scale into e4m3 normal range
#define SCL1     (C_SCALE / XSCALE) // logit = SCL1 * rcol * acc
#define SIMSCL   (1.0f / (XSCALE * XSCALE))
#define SCALE1   0x7F7F7F7F         // packed E8M0 = 1.0 in every byte

typedef float floatx4 __attribute__((ext_vector_type(4)));
typedef float f32x16  __attribute__((ext_vector_type(16)));
typedef int   v8i     __attribute__((ext_vector_type(8)));
typedef unsigned char u8;

// ---- workspace layout (bytes) ----
#define O_ALIGN  ((size_t)0)         // f32 align_sum
#define O_INST   ((size_t)64)        // f32 instance-CE sum
#define O_FIN    ((size_t)128)       // int fin counter (merge blocks)
#define O_COLSQ  ((size_t)256)       // NPAD f32  (ends 44288)
#define O_XN     ((size_t)44288)     // 2048*2048 fp8 (normalized [v;t], x16)
#define O_WT     ((size_t)4238592)   // NPAD*2048 fp8 (W^T, raw values)
#define O_PSUM   ((size_t)26782976)  // 2048*NPART f32
#define O_LL     ((size_t)28192000)  // 2048 f32 label logits
// zeroed prefix: [0, O_XN)

#define PREP_WBLOCKS (43 * 32)       // 1376: 256-class x 64-feature tiles
#define PREP_TOTAL   (PREP_WBLOCKS + M1)

__device__ inline float softplusf(float x) {
    return (x > 20.f) ? x : log1pf(expf(x));
}

// async 16B global -> LDS (wave-uniform base + lane*16; layout is lane-linear)
__device__ inline void gll16(const void* g, void* l) {
    __builtin_amdgcn_global_load_lds(
        (const __attribute__((address_space(1))) unsigned int*)g,
        (__attribute__((address_space(3))) unsigned int*)l, 16, 0, 0);
}

__device__ inline unsigned int pack4_fp8(float a, float b, float c, float d) {
    unsigned int p = __builtin_amdgcn_cvt_pk_fp8_f32(a, b, 0, false);
    p = __builtin_amdgcn_cvt_pk_fp8_f32(c, d, p, true);
    return p;  // bytes: a,b,c,d
}

// XOR swizzle on 16B-chunk index (self-inverse) — measured 0 bank conflicts (R5)
__device__ inline int swz(int c) { return c ^ ((c >> 4) & 7); }

// ---------------- fused prep (unchanged) ----------------
__global__ __launch_bounds__(256) void k_prep(const float* __restrict__ vis,
                                              const float* __restrict__ txt,
                                              const float* __restrict__ W,
                                              u8* __restrict__ Xn,
                                              u8* __restrict__ WT,
                                              float* __restrict__ colsq) {
    __shared__ u8 tileT[1024 * 16];     // 16 KB: 1024 16B chunks (class x f-quad)
    __shared__ float cps[4][256];
    __shared__ float sb[256];
    int t = threadIdx.x;
    if (blockIdx.x < PREP_WBLOCKS) {
        int c0 = (blockIdx.x % 43) * 256, f0 = (blockIdx.x / 43) * 64;
        int w = t >> 6, l = t & 63;
        int cbase = c0 + 4 * l;              // this thread's 4 classes
        unsigned int chunks[4][4];           // [class j][row-quad q]
        float ssq0 = 0.f, ssq1 = 0.f, ssq2 = 0.f, ssq3 = 0.f;
        #pragma unroll
        for (int q = 0; q < 4; ++q) {
            float4 row[4];
            #pragma unroll
            for (int rr = 0; rr < 4; ++rr) {
                int f = f0 + w * 16 + q * 4 + rr;
                const float* p = W + (size_t)f * NCLS + cbase;
                float4 v;
                if (cbase + 3 < NCLS) {
                    __builtin_memcpy(&v, p, 16);   // HW unaligned global load
                } else {
                    v.x = (cbase + 0 < NCLS) ? p[0] : 0.f;
                    v.y = (cbase + 1 < NCLS) ? p[1] : 0.f;
                    v.z = (cbase + 2 < NCLS) ? p[2] : 0.f;
                    v.w = (cbase + 3 < NCLS) ? p[3] : 0.f;
                }
                row[rr] = v;
            }
            chunks[0][q] = pack4_fp8(row[0].x, row[1].x, row[2].x, row[3].x);
            chunks[1][q] = pack4_fp8(row[0].y, row[1].y, row[2].y, row[3].y);
            chunks[2][q] = pack4_fp8(row[0].z, row[1].z, row[2].z, row[3].z);
            chunks[3][q] = pack4_fp8(row[0].w, row[1].w, row[2].w, row[3].w);
            #pragma unroll
            for (int rr = 0; rr < 4; ++rr) {
                ssq0 += row[rr].x * row[rr].x;
                ssq1 += row[rr].y * row[rr].y;
                ssq2 += row[rr].z * row[rr].z;
                ssq3 += row[rr].w * row[rr].w;
            }
        }
        #pragma unroll
        for (int j = 0; j < 4; ++j) {
            int L = (4 * l + j) * 4 + w;     // logical chunk: class-local * 4 + f-quad
            int P = L ^ ((L >> 4) & 7);
            *(uint4*)(tileT + P * 16) =
                make_uint4(chunks[j][0], chunks[j][1], chunks[j][2], chunks[j][3]);
        }
        *(float4*)&cps[w][4 * l] = make_float4(ssq0, ssq1, ssq2, ssq3);
        __syncthreads();
        int c = c0 + t;
        uint4 och[4];
        #pragma unroll
        for (int w2 = 0; w2 < 4; ++w2) {
            int L = t * 4 + w2;
            int P = L ^ ((L >> 4) & 7);
            och[w2] = *(const uint4*)(tileT + P * 16);
        }
        uint4* dst = (uint4*)(WT + (size_t)c * FEAT + f0);
        dst[0] = och[0]; dst[1] = och[1]; dst[2] = och[2]; dst[3] = och[3];
        float s = cps[0][t] + cps[1][t] + cps[2][t] + cps[3][t];
        if (c < NCLS) atomicAdd(&colsq[c], s);
    } else {
        int r = blockIdx.x - PREP_WBLOCKS;
        const float* src = (r < BATCH) ? (vis + (size_t)r * FEAT)
                                       : (txt + (size_t)(r - BATCH) * FEAT);
        float4 x0 = ((const float4*)src)[t];
        float4 x1 = ((const float4*)src)[t + 256];
        float ss = x0.x*x0.x + x0.y*x0.y + x0.z*x0.z + x0.w*x0.w
                 + x1.x*x1.x + x1.y*x1.y + x1.z*x1.z + x1.w*x1.w;
        sb[t] = ss; __syncthreads();
        for (int s = 128; s > 0; s >>= 1) { if (t < s) sb[t] += sb[t + s]; __syncthreads(); }
        float rn = rsqrtf(sb[0]) * XSCALE;
        unsigned int* dst = (unsigned int*)(Xn + (size_t)r * FEAT);
        dst[t]       = pack4_fp8(x0.x*rn, x0.y*rn, x0.z*rn, x0.w*rn);
        dst[t + 256] = pack4_fp8(x1.x*rn, x1.y*rn, x1.z*rn, x1.w*rn);
    }
}

// ---------------- fused GEMM: lse tiles (y<86) + sim tiles (y>=86) ----------------
// 128x128 tile, BK=64 fp8, double-buffered, T3 minimum-2-phase schedule:
//   STAGE(next buf) ; COMPUTE(cur buf) ; vmcnt(0)+s_barrier     (ONE per K-step)
// Overwrite-safety: each wave's lgkmcnt-waited MFMAs complete its ds_reads of
// buf X before it reaches the barrier at the end of the step that computed X;
// the STAGE that overwrites X comes after that barrier. NO sched_barrier(0)
// (R1 post-mortem: it replicated m141's 1.7x regression by defeating the
// compiler scheduler). Compiler handles lgkmcnt for ds_read->MFMA dataflow.
// Wave tile 64x64 = 2x2 of 32x32. A frag: row=lane&31, K-half=lane>>5, 32 bytes.
// C/D: col=lane&31, row=(reg&3)+8*(reg>>2)+4*(lane>>5).
__global__ __launch_bounds__(256) void k_gemm(const u8* __restrict__ Xn,
                                              const u8* __restrict__ WT,
                                              const float* __restrict__ colsq,
                                              const int* __restrict__ labels,
                                              float* __restrict__ psum,
                                              float* __restrict__ ll,
                                              float* __restrict__ align_sum) {
    __shared__ u8 As[2 * 128 * 64], Bs[2 * 128 * 64];   // 16 KB + 16 KB (dbuf)
    f32x16 acc[2][2] = {};
    const int t = threadIdx.x;
    const bool is_sim = (blockIdx.y >= NT1);
    int m0, n0;
    const u8 *A, *B;
    if (!is_sim) {
        m0 = blockIdx.x * 128; n0 = blockIdx.y * 128;
        A = Xn; B = WT;
    } else {
        int s = (blockIdx.y - NT1) * 16 + blockIdx.x;   // 0..63
        m0 = (s >> 3) * 128; n0 = (s & 7) * 128;
        A = Xn; B = Xn + (size_t)BATCH * FEAT;
    }
    const int c0s = swz(t), c1s = swz(256 + t);
    const int ra0 = c0s >> 2, h0 = c0s & 3;
    const int ra1 = c1s >> 2, h1 = c1s & 3;
    const u8* Ag0 = A + (size_t)(m0 + ra0) * FEAT + h0 * 16;
    const u8* Ag1 = A + (size_t)(m0 + ra1) * FEAT + h1 * 16;
    const u8* Bg0 = B + (size_t)(n0 + ra0) * FEAT + h0 * 16;
    const u8* Bg1 = B + (size_t)(n0 + ra1) * FEAT + h1 * 16;
    u8* lA0 = As + t * 16;
    u8* lA1 = As + 4096 + t * 16;
    u8* lB0 = Bs + t * 16;
    u8* lB1 = Bs + 4096 + t * 16;

    const int wave = t >> 6, lane = t & 63;
    const int wm = wave >> 1, wn = wave & 1;
    const int l32 = lane & 31, kh = lane >> 5;
    // fragment read pointers (buffer 0 base): logical chunk = row*4 + kh*2 + c
    const uint4* Ard[2][2]; const uint4* Brd[2][2];
    #pragma unroll
    for (int i = 0; i < 2; ++i) {
        #pragma unroll
        for (int c = 0; c < 2; ++c) {
            Ard[i][c] = (const uint4*)(As + swz((wm*64 + i*32 + l32)*4 + kh*2 + c) * 16);
            Brd[i][c] = (const uint4*)(Bs + swz((wn*64 + i*32 + l32)*4 + kh*2 + c) * 16);
        }
    }

#define STAGE(buf) do { \
        gll16(Ag0, lA0 + (buf) * 8192); \
        gll16(Ag1, lA1 + (buf) * 8192); \
        gll16(Bg0, lB0 + (buf) * 8192); \
        gll16(Bg1, lB1 + (buf) * 8192); \
        Ag0 += 64; Ag1 += 64; Bg0 += 64; Bg1 += 64; \
    } while (0)

    // One drain+barrier per K-step. vmcnt(0) waits this wave's stage loads
    // (issued ~one compute-phase ago -> latency partially hidden); raw
    // s_barrier (no compiler-added lgkmcnt/vmcnt full drain).
#define WAITB() do { \
        asm volatile("s_waitcnt vmcnt(0)" ::: "memory"); \
        __builtin_amdgcn_s_barrier(); \
    } while (0)

#define COMPUTE(buf) do { \
        v8i a[2], b[2]; \
        _Pragma("unroll") \
        for (int i = 0; i < 2; ++i) { \
            ((uint4*)&a[i])[0] = *(const uint4*)((const u8*)Ard[i][0] + (buf) * 8192); \
            ((uint4*)&a[i])[1] = *(const uint4*)((const u8*)Ard[i][1] + (buf) * 8192); \
            ((uint4*)&b[i])[0] = *(const uint4*)((const u8*)Brd[i][0] + (buf) * 8192); \
            ((uint4*)&b[i])[1] = *(const uint4*)((const u8*)Brd[i][1] + (buf) * 8192); \
        } \
        _Pragma("unroll") \
        for (int i = 0; i < 2; ++i) \
            _Pragma("unroll") \
            for (int j = 0; j < 2; ++j) \
                acc[i][j] = __builtin_amdgcn_mfma_scale_f32_32x32x64_f8f6f4( \
                    a[i], b[j], acc[i][j], 0, 0, 0, SCALE1, 0, SCALE1); \
    } while (0)

    // tiles: 32 (FEAT/64). buf0 <- even tiles, buf1 <- odd tiles.
    STAGE(0);                                   // tile 0 -> buf0
    WAITB();                                    // buf0 ready (full latency, once)
    for (int kt = 0; kt < FEAT / 64 - 2; kt += 2) {
        STAGE(1);                               // tile kt+1 -> buf1
        COMPUTE(0);                             // tile kt
        WAITB();
        STAGE(0);                               // tile kt+2 -> buf0
        COMPUTE(1);                             // tile kt+1
        WAITB();
    }
    STAGE(1);                                   // tile 31 -> buf1
    COMPUTE(0);                                 // tile 30
    WAITB();
    COMPUTE(1);                                 // tile 31
#undef STAGE
#undef WAITB
#undef COMPUTE

    if (!is_sim) {
        // ---- LSE epilogue: fixed-max sum of exp(logit - 28) + label-logit scatter ----
        float rcol[2]; bool val[2]; int ncol[2];
        #pragma unroll
        for (int j = 0; j < 2; ++j) {
            ncol[j] = n0 + wn*64 + j*32 + l32;
            val[j] = (ncol[j] < NCLS);
            rcol[j] = val[j] ? (SCL1 * rsqrtf(colsq[ncol[j]])) : 0.f;
        }
        const int pidx = blockIdx.y * 2 + wn;
        #pragma unroll
        for (int i = 0; i < 2; ++i) {
            #pragma unroll
            for (int reg = 0; reg < 16; ++reg) {
                int m = m0 + wm*64 + i*32 + (reg & 3) + 8*(reg >> 2) + 4*kh;
                int lm = labels[m & (BATCH - 1)];
                float s = 0.f;
                #pragma unroll
                for (int j = 0; j < 2; ++j) {
                    if (val[j]) {
                        float v = acc[i][j][reg] * rcol[j];
                        if (ncol[j] == lm) ll[m] = v;
                        s += __expf(v - C_SCALE);
                    }
                }
                #pragma unroll
                for (int off = 1; off < 32; off <<= 1) s += __shfl_xor(s, off);
                if (l32 == 0) psum[(size_t)m * NPART + pidx] = s;
            }
        }
    } else {
        // ---- sim epilogue: masked softplus sum ----
        int ln[2];
        #pragma unroll
        for (int j = 0; j < 2; ++j) ln[j] = labels[n0 + wn*64 + j*32 + l32];
        float tot = 0.f;
        #pragma unroll
        for (int i = 0; i < 2; ++i) {
            #pragma unroll
            for (int reg = 0; reg < 16; ++reg) {
                int m = m0 + wm*64 + i*32 + (reg & 3) + 8*(reg >> 2) + 4*kh;
                int lm = labels[m];
                #pragma unroll
                for (int j = 0; j < 2; ++j) {
                    float s = acc[i][j][reg] * SIMSCL;
                    float arg = (lm == ln[j]) ? (-C_SPOS * (s - C_ALPHA))
                                              : ( C_SNEG * (s - C_BETA));
                    tot += softplusf(arg);
                }
            }
        }
        #pragma unroll
        for (int off = 1; off < 64; off <<= 1) tot += __shfl_xor(tot, off);
        if (lane == 0) atomicAdd(align_sum, tot);
    }
}

// ---------------- merge psum partials -> CE sum; last block writes out ----------------
__global__ __launch_bounds__(256) void k_merge(const float* __restrict__ psum,
                                               const float* __restrict__ ll,
                                               float* __restrict__ inst_sum,
                                               const float* __restrict__ align_sum,
                                               int* __restrict__ fin,
                                               float* __restrict__ out) {
    int r = blockIdx.x, t = threadIdx.x;
    float sm = (t < NPART) ? psum[(size_t)r * NPART + t] : 0.f;
    __shared__ float sb[256];
    sb[t] = sm; __syncthreads();
    for (int s = 128; s > 0; s >>= 1) { if (t < s) sb[t] += sb[t+s]; __syncthreads(); }
    if (t == 0) {
        atomicAdd(inst_sum, C_SCALE + logf(sb[0]) - ll[r]);
        __threadfence();
        if (atomicAdd(fin, 1) == M1 - 1) {          // last merge block
            __threadfence();
            float is = atomicAdd(inst_sum, 0.f);    // atomic read, device scope
            float as = atomicAdd((float*)align_sum, 0.f);
            out[0] = is / (float)BATCH;
            out[1] = as * 2.f / (float)BATCH;
        }
    }
}

extern "C" void kernel_launch(void* const* d_in, const int* in_sizes, int n_in,
                              void* d_out, int out_size, void* d_ws, size_t ws_size,
                              hipStream_t stream) {
    const float* vis    = (const float*)d_in[0];
    const float* txt    = (const float*)d_in[1];
    const int*   labels = (const int*)  d_in[2];
    const float* W      = (const float*)d_in[3];
    float* out = (float*)d_out;
    char*  ws  = (char*)d_ws;

    float* align_sum = (float*)(ws + O_ALIGN);
    float* inst_sum  = (float*)(ws + O_INST);
    int*   fin       = (int*)  (ws + O_FIN);
    float* colsq     = (float*)(ws + O_COLSQ);
    u8* Xn = (u8*)(ws + O_XN);
    u8* WT = (u8*)(ws + O_WT);
    float* psum = (float*)(ws + O_PSUM);
    float* ll   = (float*)(ws + O_LL);

    hipMemsetAsync(ws, 0, O_XN, stream);  // zero align/inst/fin/colsq

    k_prep <<<dim3(PREP_TOTAL), 256, 0, stream>>>(vis, txt, W, Xn, WT, colsq);
    k_gemm <<<dim3(M1 / 128, NT1 + 4), 256, 0, stream>>>(Xn, WT, colsq, labels,
                                                         psum, ll, align_sum);
    k_merge<<<dim3(M1), 256, 0, stream>>>(psum, ll, inst_sum, align_sum, fin, out);
}

// Round 3
// 332.684 us; speedup vs baseline: 1.1082x; 1.1065x over previous
//
#include <hip/hip_runtime.h>
#include <hip/hip_bf16.h>
#include <math.h>

// Problem constants
#define BATCH 1024
#define FEAT  2048
#define NCLS  11003
#define NPAD  11008      // 86 * 128
#define NT1   86         // N tiles for gemm1
#define NPART (NT1 * 2)  // psum partials per row (2 waves in N per tile)
#define M1    2048       // stacked [v; t]
#define C_SCALE  28.0f
#define C_ALPHA  0.6f
#define C_BETA   0.4f
#define C_SPOS   10.0f
#define C_SNEG   40.0f
#define XSCALE   16.0f              // Xn pre-scale into e4m3 normal range
#define SCL1     (C_SCALE / XSCALE) // logit = SCL1 * rcol * acc
#define SIMSCL   (1.0f / (XSCALE * XSCALE))
#define SCALE1   0x7F7F7F7F         // packed E8M0 = 1.0 in every byte

typedef float floatx4 __attribute__((ext_vector_type(4)));
typedef float f32x16  __attribute__((ext_vector_type(16)));
typedef int   v8i     __attribute__((ext_vector_type(8)));
typedef unsigned char u8;

// ---- workspace layout (bytes) ----
#define O_ALIGN  ((size_t)0)         // f32 align_sum
#define O_INST   ((size_t)64)        // f32 instance-CE sum
#define O_FIN    ((size_t)128)       // int fin counter (merge blocks)
#define O_COLSQ  ((size_t)256)       // NPAD f32  (ends 44288)
#define O_XN     ((size_t)44288)     // 2048*2048 fp8 (normalized [v;t], x16)
#define O_WT     ((size_t)4238592)   // NPAD*2048 fp8 (W^T, raw values)
#define O_PSUM   ((size_t)26782976)  // 2048*NPART f32
#define O_LL     ((size_t)28192000)  // 2048 f32 label logits
// zeroed prefix: [0, O_XN)

#define PREP_WBLOCKS (43 * 32)       // 1376: 256-class x 64-feature tiles
#define PREP_TOTAL   (PREP_WBLOCKS + M1)

#define GEMM_BLOCKS  (16 * (NT1 + 4))   // 1440 = 8 XCDs * 180
#define MERGE_BLOCKS 256
#define ROWS_PER_MB  (M1 / MERGE_BLOCKS)  // 8

__device__ inline float softplusf(float x) {
    return (x > 20.f) ? x : log1pf(expf(x));
}

// async 16B global -> LDS (wave-uniform base + lane*16; layout is lane-linear)
__device__ inline void gll16(const void* g, void* l) {
    __builtin_amdgcn_global_load_lds(
        (const __attribute__((address_space(1))) unsigned int*)g,
        (__attribute__((address_space(3))) unsigned int*)l, 16, 0, 0);
}

__device__ inline unsigned int pack4_fp8(float a, float b, float c, float d) {
    unsigned int p = __builtin_amdgcn_cvt_pk_fp8_f32(a, b, 0, false);
    p = __builtin_amdgcn_cvt_pk_fp8_f32(c, d, p, true);
    return p;  // bytes: a,b,c,d
}

// XOR swizzle on 16B-chunk index (self-inverse) — measured 0 bank conflicts (R5)
__device__ inline int swz(int c) { return c ^ ((c >> 4) & 7); }

// ---------------- fused prep (unchanged) ----------------
__global__ __launch_bounds__(256) void k_prep(const float* __restrict__ vis,
                                              const float* __restrict__ txt,
                                              const float* __restrict__ W,
                                              u8* __restrict__ Xn,
                                              u8* __restrict__ WT,
                                              float* __restrict__ colsq) {
    __shared__ u8 tileT[1024 * 16];     // 16 KB: 1024 16B chunks (class x f-quad)
    __shared__ float cps[4][256];
    __shared__ float sb[256];
    int t = threadIdx.x;
    if (blockIdx.x < PREP_WBLOCKS) {
        int c0 = (blockIdx.x % 43) * 256, f0 = (blockIdx.x / 43) * 64;
        int w = t >> 6, l = t & 63;
        int cbase = c0 + 4 * l;              // this thread's 4 classes
        unsigned int chunks[4][4];           // [class j][row-quad q]
        float ssq0 = 0.f, ssq1 = 0.f, ssq2 = 0.f, ssq3 = 0.f;
        #pragma unroll
        for (int q = 0; q < 4; ++q) {
            float4 row[4];
            #pragma unroll
            for (int rr = 0; rr < 4; ++rr) {
                int f = f0 + w * 16 + q * 4 + rr;
                const float* p = W + (size_t)f * NCLS + cbase;
                float4 v;
                if (cbase + 3 < NCLS) {
                    __builtin_memcpy(&v, p, 16);   // HW unaligned global load
                } else {
                    v.x = (cbase + 0 < NCLS) ? p[0] : 0.f;
                    v.y = (cbase + 1 < NCLS) ? p[1] : 0.f;
                    v.z = (cbase + 2 < NCLS) ? p[2] : 0.f;
                    v.w = (cbase + 3 < NCLS) ? p[3] : 0.f;
                }
                row[rr] = v;
            }
            chunks[0][q] = pack4_fp8(row[0].x, row[1].x, row[2].x, row[3].x);
            chunks[1][q] = pack4_fp8(row[0].y, row[1].y, row[2].y, row[3].y);
            chunks[2][q] = pack4_fp8(row[0].z, row[1].z, row[2].z, row[3].z);
            chunks[3][q] = pack4_fp8(row[0].w, row[1].w, row[2].w, row[3].w);
            #pragma unroll
            for (int rr = 0; rr < 4; ++rr) {
                ssq0 += row[rr].x * row[rr].x;
                ssq1 += row[rr].y * row[rr].y;
                ssq2 += row[rr].z * row[rr].z;
                ssq3 += row[rr].w * row[rr].w;
            }
        }
        #pragma unroll
        for (int j = 0; j < 4; ++j) {
            int L = (4 * l + j) * 4 + w;     // logical chunk: class-local * 4 + f-quad
            int P = L ^ ((L >> 4) & 7);
            *(uint4*)(tileT + P * 16) =
                make_uint4(chunks[j][0], chunks[j][1], chunks[j][2], chunks[j][3]);
        }
        *(float4*)&cps[w][4 * l] = make_float4(ssq0, ssq1, ssq2, ssq3);
        __syncthreads();
        int c = c0 + t;
        uint4 och[4];
        #pragma unroll
        for (int w2 = 0; w2 < 4; ++w2) {
            int L = t * 4 + w2;
            int P = L ^ ((L >> 4) & 7);
            och[w2] = *(const uint4*)(tileT + P * 16);
        }
        uint4* dst = (uint4*)(WT + (size_t)c * FEAT + f0);
        dst[0] = och[0]; dst[1] = och[1]; dst[2] = och[2]; dst[3] = och[3];
        float s = cps[0][t] + cps[1][t] + cps[2][t] + cps[3][t];
        if (c < NCLS) atomicAdd(&colsq[c], s);
    } else {
        int r = blockIdx.x - PREP_WBLOCKS;
        const float* src = (r < BATCH) ? (vis + (size_t)r * FEAT)
                                       : (txt + (size_t)(r - BATCH) * FEAT);
        float4 x0 = ((const float4*)src)[t];
        float4 x1 = ((const float4*)src)[t + 256];
        float ss = x0.x*x0.x + x0.y*x0.y + x0.z*x0.z + x0.w*x0.w
                 + x1.x*x1.x + x1.y*x1.y + x1.z*x1.z + x1.w*x1.w;
        sb[t] = ss; __syncthreads();
        for (int s = 128; s > 0; s >>= 1) { if (t < s) sb[t] += sb[t + s]; __syncthreads(); }
        float rn = rsqrtf(sb[0]) * XSCALE;
        unsigned int* dst = (unsigned int*)(Xn + (size_t)r * FEAT);
        dst[t]       = pack4_fp8(x0.x*rn, x0.y*rn, x0.z*rn, x0.w*rn);
        dst[t + 256] = pack4_fp8(x1.x*rn, x1.y*rn, x1.z*rn, x1.w*rn);
    }
}

// ---------------- fused GEMM: lse tiles (yw<86) + sim tiles (yw>=86) ----------------
// R3: EXACT R0 loop structure restored (single buffer, 2x __syncthreads per
// K-step). R1/R2 post-mortem: explicit dbuf + raw s_barrier + vmcnt(0) was 2x
// SLOWER (204-209 µs vs 101.6) regardless of sched_barrier — compiler aliasing
// guards serialize the loop and 32 KB LDS halves resident blocks, killing the
// inter-block overlap that actually hides latency here (m114). Do not retry
// source-level pipelining on this 128^2 template.
// NEW: T1 XCD-chunked work swizzle. Grid 1440 = 8*180, HW round-robins blocks
// across 8 XCDs by linear id; remap work = (bid&7)*180 + (bid>>3) so each XCD
// processes 180 consecutive tiles (~11 N-panels): per-XCD L2 footprint drops
// from ~26.5 MB to ~7 MB. Signature to check: FETCH_SIZE 100 MB -> 35-60 MB.
// Wave tile 64x64 = 2x2 of 32x32. A frag: row=lane&31, K-half=lane>>5, 32 bytes.
// C/D: col=lane&31, row=(reg&3)+8*(reg>>2)+4*(lane>>5).
__global__ __launch_bounds__(256) void k_gemm(const u8* __restrict__ Xn,
                                              const u8* __restrict__ WT,
                                              const float* __restrict__ colsq,
                                              const int* __restrict__ labels,
                                              float* __restrict__ psum,
                                              float* __restrict__ ll,
                                              float* __restrict__ align_sum) {
    __shared__ u8 As[128 * 64], Bs[128 * 64];   // 8 KB + 8 KB
    f32x16 acc[2][2] = {};
    const int t = threadIdx.x;
    // XCD-chunked bijective swizzle (1440 = 8 * 180)
    const int bid  = blockIdx.x + (blockIdx.y << 4);      // gridDim.x == 16
    const int work = (bid & 7) * 180 + (bid >> 3);
    const int xw = work & 15, yw = work >> 4;
    const bool is_sim = (yw >= NT1);
    int m0, n0;
    const u8 *A, *B;
    if (!is_sim) {
        m0 = xw * 128; n0 = yw * 128;
        A = Xn; B = WT;
    } else {
        int s = (yw - NT1) * 16 + xw;                     // 0..63
        m0 = (s >> 3) * 128; n0 = (s & 7) * 128;
        A = Xn; B = Xn + (size_t)BATCH * FEAT;
    }
    const int c0s = swz(t), c1s = swz(256 + t);
    const int ra0 = c0s >> 2, h0 = c0s & 3;
    const int ra1 = c1s >> 2, h1 = c1s & 3;
    const u8* Ag0 = A + (size_t)(m0 + ra0) * FEAT + h0 * 16;
    const u8* Ag1 = A + (size_t)(m0 + ra1) * FEAT + h1 * 16;
    const u8* Bg0 = B + (size_t)(n0 + ra0) * FEAT + h0 * 16;
    const u8* Bg1 = B + (size_t)(n0 + ra1) * FEAT + h1 * 16;
    u8* lA0 = As + t * 16;
    u8* lA1 = As + 4096 + t * 16;
    u8* lB0 = Bs + t * 16;
    u8* lB1 = Bs + 4096 + t * 16;

    const int wave = t >> 6, lane = t & 63;
    const int wm = wave >> 1, wn = wave & 1;
    const int l32 = lane & 31, kh = lane >> 5;
    // fragment read pointers: logical chunk = row*4 + kh*2 + c
    const uint4* Ard[2][2]; const uint4* Brd[2][2];
    #pragma unroll
    for (int i = 0; i < 2; ++i) {
        #pragma unroll
        for (int c = 0; c < 2; ++c) {
            Ard[i][c] = (const uint4*)(As + swz((wm*64 + i*32 + l32)*4 + kh*2 + c) * 16);
            Brd[i][c] = (const uint4*)(Bs + swz((wn*64 + i*32 + l32)*4 + kh*2 + c) * 16);
        }
    }
    for (int kt = 0; kt < FEAT / 64; ++kt) {
        __syncthreads();
        gll16(Ag0, lA0);
        gll16(Ag1, lA1);
        gll16(Bg0, lB0);
        gll16(Bg1, lB1);
        Ag0 += 64; Ag1 += 64; Bg0 += 64; Bg1 += 64;
        __syncthreads();
        v8i a[2], b[2];
        #pragma unroll
        for (int i = 0; i < 2; ++i) {
            ((uint4*)&a[i])[0] = *Ard[i][0];
            ((uint4*)&a[i])[1] = *Ard[i][1];
            ((uint4*)&b[i])[0] = *Brd[i][0];
            ((uint4*)&b[i])[1] = *Brd[i][1];
        }
        #pragma unroll
        for (int i = 0; i < 2; ++i)
            #pragma unroll
            for (int j = 0; j < 2; ++j)
                acc[i][j] = __builtin_amdgcn_mfma_scale_f32_32x32x64_f8f6f4(
                    a[i], b[j], acc[i][j], 0, 0, 0, SCALE1, 0, SCALE1);
    }

    if (!is_sim) {
        // ---- LSE epilogue: fixed-max sum of exp(logit - 28) + label-logit scatter ----
        float rcol[2]; bool val[2]; int ncol[2];
        #pragma unroll
        for (int j = 0; j < 2; ++j) {
            ncol[j] = n0 + wn*64 + j*32 + l32;
            val[j] = (ncol[j] < NCLS);
            rcol[j] = val[j] ? (SCL1 * rsqrtf(colsq[ncol[j]])) : 0.f;
        }
        const int pidx = yw * 2 + wn;
        #pragma unroll
        for (int i = 0; i < 2; ++i) {
            #pragma unroll
            for (int reg = 0; reg < 16; ++reg) {
                int m = m0 + wm*64 + i*32 + (reg & 3) + 8*(reg >> 2) + 4*kh;
                int lm = labels[m & (BATCH - 1)];
                float s = 0.f;
                #pragma unroll
                for (int j = 0; j < 2; ++j) {
                    if (val[j]) {
                        float v = acc[i][j][reg] * rcol[j];
                        if (ncol[j] == lm) ll[m] = v;
                        s += __expf(v - C_SCALE);
                    }
                }
                #pragma unroll
                for (int off = 1; off < 32; off <<= 1) s += __shfl_xor(s, off);
                if (l32 == 0) psum[(size_t)m * NPART + pidx] = s;
            }
        }
    } else {
        // ---- sim epilogue: masked softplus sum ----
        int ln[2];
        #pragma unroll
        for (int j = 0; j < 2; ++j) ln[j] = labels[n0 + wn*64 + j*32 + l32];
        float tot = 0.f;
        #pragma unroll
        for (int i = 0; i < 2; ++i) {
            #pragma unroll
            for (int reg = 0; reg < 16; ++reg) {
                int m = m0 + wm*64 + i*32 + (reg & 3) + 8*(reg >> 2) + 4*kh;
                int lm = labels[m];
                #pragma unroll
                for (int j = 0; j < 2; ++j) {
                    float s = acc[i][j][reg] * SIMSCL;
                    float arg = (lm == ln[j]) ? (-C_SPOS * (s - C_ALPHA))
                                              : ( C_SNEG * (s - C_BETA));
                    tot += softplusf(arg);
                }
            }
        }
        #pragma unroll
        for (int off = 1; off < 64; off <<= 1) tot += __shfl_xor(tot, off);
        if (lane == 0) atomicAdd(align_sum, tot);
    }
}

// ---------------- merge psum partials -> CE sum; last block writes out ----------------
// R3: 256 blocks x 8 rows (was 2048 blocks x 1 row). One same-address atomicAdd
// per block instead of 2048 serialized ones.
__global__ __launch_bounds__(256) void k_merge(const float* __restrict__ psum,
                                               const float* __restrict__ ll,
                                               float* __restrict__ inst_sum,
                                               const float* __restrict__ align_sum,
                                               int* __restrict__ fin,
                                               float* __restrict__ out) {
    const int t = threadIdx.x;
    const int g = t >> 5, l = t & 31;             // 8 groups of 32 lanes
    const int r = blockIdx.x * ROWS_PER_MB + g;
    const float* pr = psum + (size_t)r * NPART;
    float s = 0.f;
    for (int p = l; p < NPART; p += 32) s += pr[p];
    #pragma unroll
    for (int off = 1; off < 32; off <<= 1) s += __shfl_xor(s, off);
    __shared__ float sb[ROWS_PER_MB];
    if (l == 0) sb[g] = C_SCALE + logf(s) - ll[r];
    __syncthreads();
    if (t == 0) {
        float ce = 0.f;
        #pragma unroll
        for (int i = 0; i < ROWS_PER_MB; ++i) ce += sb[i];
        atomicAdd(inst_sum, ce);
        __threadfence();
        if (atomicAdd(fin, 1) == MERGE_BLOCKS - 1) {    // last merge block
            __threadfence();
            float is = atomicAdd(inst_sum, 0.f);        // atomic read, device scope
            float as = atomicAdd((float*)align_sum, 0.f);
            out[0] = is / (float)BATCH;
            out[1] = as * 2.f / (float)BATCH;
        }
    }
}

extern "C" void kernel_launch(void* const* d_in, const int* in_sizes, int n_in,
                              void* d_out, int out_size, void* d_ws, size_t ws_size,
                              hipStream_t stream) {
    const float* vis    = (const float*)d_in[0];
    const float* txt    = (const float*)d_in[1];
    const int*   labels = (const int*)  d_in[2];
    const float* W      = (const float*)d_in[3];
    float* out = (float*)d_out;
    char*  ws  = (char*)d_ws;

    float* align_sum = (float*)(ws + O_ALIGN);
    float* inst_sum  = (float*)(ws + O_INST);
    int*   fin       = (int*)  (ws + O_FIN);
    float* colsq     = (float*)(ws + O_COLSQ);
    u8* Xn = (u8*)(ws + O_XN);
    u8* WT = (u8*)(ws + O_WT);
    float* psum = (float*)(ws + O_PSUM);
    float* ll   = (float*)(ws + O_LL);

    hipMemsetAsync(ws, 0, O_XN, stream);  // zero align/inst/fin/colsq

    k_prep <<<dim3(PREP_TOTAL), 256, 0, stream>>>(vis, txt, W, Xn, WT, colsq);
    k_gemm <<<dim3(M1 / 128, NT1 + 4), 256, 0, stream>>>(Xn, WT, colsq, labels,
                                                         psum, ll, align_sum);
    k_merge<<<dim3(MERGE_BLOCKS), 256, 0, stream>>>(psum, ll, inst_sum, align_sum,
                                                    fin, out);
}

// Round 4
// 258.988 us; speedup vs baseline: 1.4236x; 1.2846x over previous
//
#include <hip/hip_runtime.h>
#include <hip/hip_bf16.h>
#include <math.h>

// Problem constants
#define BATCH 1024
#define FEAT  2048
#define NCLS  11003
#define NPAD  11008      // 86 * 128
#define NT1   86         // N tiles for gemm1
#define NPART (NT1 * 2)  // psum partials per row (2 waves in N per tile)
#define M1    2048       // stacked [v; t]
#define C_SCALE  28.0f
#define C_ALPHA  0.6f
#define C_BETA   0.4f
#define C_SPOS   10.0f
#define C_SNEG   40.0f
#define XSCALE   16.0f              // Xn pre-scale into e4m3 normal range
#define SCL1     (C_SCALE / XSCALE) // logit = SCL1 * rcol * acc
#define SIMSCL   (1.0f / (XSCALE * XSCALE))
#define SCALE1   0x7F7F7F7F         // packed E8M0 = 1.0 in every byte

typedef float floatx4 __attribute__((ext_vector_type(4)));
typedef float f32x16  __attribute__((ext_vector_type(16)));
typedef int   v8i     __attribute__((ext_vector_type(8)));
typedef unsigned char u8;

// ---- workspace layout (bytes) ----
#define O_ALIGN  ((size_t)0)         // f32 align_sum
#define O_INST   ((size_t)64)        // f32 instance-CE sum
#define O_FIN    ((size_t)128)       // int fin counter (merge blocks)
#define O_COLSQ  ((size_t)256)       // NPAD f32  (ends 44288)
#define O_XN     ((size_t)44288)     // 2048*2048 fp8 (normalized [v;t], x16)
#define O_WT     ((size_t)4238592)   // NPAD*2048 fp8 (W^T, raw values)
#define O_PSUM   ((size_t)26782976)  // 2048*NPART f32
#define O_LL     ((size_t)28192000)  // 2048 f32 label logits
// zeroed prefix: [0, O_XN)

#define PREP_WBLOCKS (43 * 32)       // 1376: 256-class x 64-feature tiles
#define PREP_TOTAL   (PREP_WBLOCKS + M1)

#define MERGE_BLOCKS 256
#define ROWS_PER_MB  (M1 / MERGE_BLOCKS)  // 8

__device__ inline float softplusf(float x) {
    return (x > 20.f) ? x : log1pf(expf(x));
}

// async 16B global -> LDS (wave-uniform base + lane*16; layout is lane-linear)
__device__ inline void gll16(const void* g, void* l) {
    __builtin_amdgcn_global_load_lds(
        (const __attribute__((address_space(1))) unsigned int*)g,
        (__attribute__((address_space(3))) unsigned int*)l, 16, 0, 0);
}

__device__ inline unsigned int pack4_fp8(float a, float b, float c, float d) {
    unsigned int p = __builtin_amdgcn_cvt_pk_fp8_f32(a, b, 0, false);
    p = __builtin_amdgcn_cvt_pk_fp8_f32(c, d, p, true);
    return p;  // bytes: a,b,c,d
}

// XOR swizzle on 16B-chunk index (self-inverse) — measured 0 bank conflicts (R5)
__device__ inline int swz(int c) { return c ^ ((c >> 4) & 7); }

// ---------------- fused prep (unchanged) ----------------
__global__ __launch_bounds__(256) void k_prep(const float* __restrict__ vis,
                                              const float* __restrict__ txt,
                                              const float* __restrict__ W,
                                              u8* __restrict__ Xn,
                                              u8* __restrict__ WT,
                                              float* __restrict__ colsq) {
    __shared__ u8 tileT[1024 * 16];     // 16 KB: 1024 16B chunks (class x f-quad)
    __shared__ float cps[4][256];
    __shared__ float sb[256];
    int t = threadIdx.x;
    if (blockIdx.x < PREP_WBLOCKS) {
        int c0 = (blockIdx.x % 43) * 256, f0 = (blockIdx.x / 43) * 64;
        int w = t >> 6, l = t & 63;
        int cbase = c0 + 4 * l;              // this thread's 4 classes
        unsigned int chunks[4][4];           // [class j][row-quad q]
        float ssq0 = 0.f, ssq1 = 0.f, ssq2 = 0.f, ssq3 = 0.f;
        #pragma unroll
        for (int q = 0; q < 4; ++q) {
            float4 row[4];
            #pragma unroll
            for (int rr = 0; rr < 4; ++rr) {
                int f = f0 + w * 16 + q * 4 + rr;
                const float* p = W + (size_t)f * NCLS + cbase;
                float4 v;
                if (cbase + 3 < NCLS) {
                    __builtin_memcpy(&v, p, 16);   // HW unaligned global load
                } else {
                    v.x = (cbase + 0 < NCLS) ? p[0] : 0.f;
                    v.y = (cbase + 1 < NCLS) ? p[1] : 0.f;
                    v.z = (cbase + 2 < NCLS) ? p[2] : 0.f;
                    v.w = (cbase + 3 < NCLS) ? p[3] : 0.f;
                }
                row[rr] = v;
            }
            chunks[0][q] = pack4_fp8(row[0].x, row[1].x, row[2].x, row[3].x);
            chunks[1][q] = pack4_fp8(row[0].y, row[1].y, row[2].y, row[3].y);
            chunks[2][q] = pack4_fp8(row[0].z, row[1].z, row[2].z, row[3].z);
            chunks[3][q] = pack4_fp8(row[0].w, row[1].w, row[2].w, row[3].w);
            #pragma unroll
            for (int rr = 0; rr < 4; ++rr) {
                ssq0 += row[rr].x * row[rr].x;
                ssq1 += row[rr].y * row[rr].y;
                ssq2 += row[rr].z * row[rr].z;
                ssq3 += row[rr].w * row[rr].w;
            }
        }
        #pragma unroll
        for (int j = 0; j < 4; ++j) {
            int L = (4 * l + j) * 4 + w;     // logical chunk: class-local * 4 + f-quad
            int P = L ^ ((L >> 4) & 7);
            *(uint4*)(tileT + P * 16) =
                make_uint4(chunks[j][0], chunks[j][1], chunks[j][2], chunks[j][3]);
        }
        *(float4*)&cps[w][4 * l] = make_float4(ssq0, ssq1, ssq2, ssq3);
        __syncthreads();
        int c = c0 + t;
        uint4 och[4];
        #pragma unroll
        for (int w2 = 0; w2 < 4; ++w2) {
            int L = t * 4 + w2;
            int P = L ^ ((L >> 4) & 7);
            och[w2] = *(const uint4*)(tileT + P * 16);
        }
        uint4* dst = (uint4*)(WT + (size_t)c * FEAT + f0);
        dst[0] = och[0]; dst[1] = och[1]; dst[2] = och[2]; dst[3] = och[3];
        float s = cps[0][t] + cps[1][t] + cps[2][t] + cps[3][t];
        if (c < NCLS) atomicAdd(&colsq[c], s);
    } else {
        int r = blockIdx.x - PREP_WBLOCKS;
        const float* src = (r < BATCH) ? (vis + (size_t)r * FEAT)
                                       : (txt + (size_t)(r - BATCH) * FEAT);
        float4 x0 = ((const float4*)src)[t];
        float4 x1 = ((const float4*)src)[t + 256];
        float ss = x0.x*x0.x + x0.y*x0.y + x0.z*x0.z + x0.w*x0.w
                 + x1.x*x1.x + x1.y*x1.y + x1.z*x1.z + x1.w*x1.w;
        sb[t] = ss; __syncthreads();
        for (int s = 128; s > 0; s >>= 1) { if (t < s) sb[t] += sb[t + s]; __syncthreads(); }
        float rn = rsqrtf(sb[0]) * XSCALE;
        unsigned int* dst = (unsigned int*)(Xn + (size_t)r * FEAT);
        dst[t]       = pack4_fp8(x0.x*rn, x0.y*rn, x0.z*rn, x0.w*rn);
        dst[t + 256] = pack4_fp8(x1.x*rn, x1.y*rn, x1.z*rn, x1.w*rn);
    }
}

// ---------------- fused GEMM: lse tiles (y<86) + sim tiles (y>=86) ----------------
// R4: byte-exact R0 structure and mapping (measured 101.6 µs, 951 TF eff).
// HISTORY — do not retry:
//  * R1/R2: explicit LDS dbuf + raw s_barrier + vmcnt(0) (w/ and w/o
//    sched_barrier) -> 204-209 µs (2x SLOWER). Compiler aliasing guards +
//    halved occupancy kill it; inter-block overlap (m114) is what hides
//    latency in this structure.
//  * R3: XCD-chunked work swizzle -> FETCH 100->45 MB but 220 µs (2.2x
//    SLOWER). Natural x-fast dispatch gives each XCD only TWO A-panels
//    (512 KB, L2-resident); chunking made per-XCD A footprint 4 MB -> L2
//    thrash on the latency-critical staging loads. Optimize L2-hit latency,
//    not FETCH volume.
// Wave tile 64x64 = 2x2 of 32x32. A frag: row=lane&31, K-half=lane>>5, 32 bytes.
// C/D: col=lane&31, row=(reg&3)+8*(reg>>2)+4*(lane>>5).
__global__ __launch_bounds__(256) void k_gemm(const u8* __restrict__ Xn,
                                              const u8* __restrict__ WT,
                                              const float* __restrict__ colsq,
                                              const int* __restrict__ labels,
                                              float* __restrict__ psum,
                                              float* __restrict__ ll,
                                              float* __restrict__ align_sum) {
    __shared__ u8 As[128 * 64], Bs[128 * 64];   // 8 KB + 8 KB
    f32x16 acc[2][2] = {};
    const int t = threadIdx.x;
    const bool is_sim = (blockIdx.y >= NT1);
    int m0, n0;
    const u8 *A, *B;
    if (!is_sim) {
        m0 = blockIdx.x * 128; n0 = blockIdx.y * 128;
        A = Xn; B = WT;
    } else {
        int s = (blockIdx.y - NT1) * 16 + blockIdx.x;   // 0..63
        m0 = (s >> 3) * 128; n0 = (s & 7) * 128;
        A = Xn; B = Xn + (size_t)BATCH * FEAT;
    }
    const int c0s = swz(t), c1s = swz(256 + t);
    const int ra0 = c0s >> 2, h0 = c0s & 3;
    const int ra1 = c1s >> 2, h1 = c1s & 3;
    const u8* Ag0 = A + (size_t)(m0 + ra0) * FEAT + h0 * 16;
    const u8* Ag1 = A + (size_t)(m0 + ra1) * FEAT + h1 * 16;
    const u8* Bg0 = B + (size_t)(n0 + ra0) * FEAT + h0 * 16;
    const u8* Bg1 = B + (size_t)(n0 + ra1) * FEAT + h1 * 16;
    u8* lA0 = As + t * 16;
    u8* lA1 = As + 4096 + t * 16;
    u8* lB0 = Bs + t * 16;
    u8* lB1 = Bs + 4096 + t * 16;

    const int wave = t >> 6, lane = t & 63;
    const int wm = wave >> 1, wn = wave & 1;
    const int l32 = lane & 31, kh = lane >> 5;
    // fragment read pointers: logical chunk = row*4 + kh*2 + c
    const uint4* Ard[2][2]; const uint4* Brd[2][2];
    #pragma unroll
    for (int i = 0; i < 2; ++i) {
        #pragma unroll
        for (int c = 0; c < 2; ++c) {
            Ard[i][c] = (const uint4*)(As + swz((wm*64 + i*32 + l32)*4 + kh*2 + c) * 16);
            Brd[i][c] = (const uint4*)(Bs + swz((wn*64 + i*32 + l32)*4 + kh*2 + c) * 16);
        }
    }
    for (int kt = 0; kt < FEAT / 64; ++kt) {
        __syncthreads();
        gll16(Ag0, lA0);
        gll16(Ag1, lA1);
        gll16(Bg0, lB0);
        gll16(Bg1, lB1);
        Ag0 += 64; Ag1 += 64; Bg0 += 64; Bg1 += 64;
        __syncthreads();
        v8i a[2], b[2];
        #pragma unroll
        for (int i = 0; i < 2; ++i) {
            ((uint4*)&a[i])[0] = *Ard[i][0];
            ((uint4*)&a[i])[1] = *Ard[i][1];
            ((uint4*)&b[i])[0] = *Brd[i][0];
            ((uint4*)&b[i])[1] = *Brd[i][1];
        }
        #pragma unroll
        for (int i = 0; i < 2; ++i)
            #pragma unroll
            for (int j = 0; j < 2; ++j)
                acc[i][j] = __builtin_amdgcn_mfma_scale_f32_32x32x64_f8f6f4(
                    a[i], b[j], acc[i][j], 0, 0, 0, SCALE1, 0, SCALE1);
    }

    if (!is_sim) {
        // ---- LSE epilogue: fixed-max sum of exp(logit - 28) + label-logit scatter ----
        float rcol[2]; bool val[2]; int ncol[2];
        #pragma unroll
        for (int j = 0; j < 2; ++j) {
            ncol[j] = n0 + wn*64 + j*32 + l32;
            val[j] = (ncol[j] < NCLS);
            rcol[j] = val[j] ? (SCL1 * rsqrtf(colsq[ncol[j]])) : 0.f;
        }
        const int pidx = blockIdx.y * 2 + wn;
        #pragma unroll
        for (int i = 0; i < 2; ++i) {
            #pragma unroll
            for (int reg = 0; reg < 16; ++reg) {
                int m = m0 + wm*64 + i*32 + (reg & 3) + 8*(reg >> 2) + 4*kh;
                int lm = labels[m & (BATCH - 1)];
                float s = 0.f;
                #pragma unroll
                for (int j = 0; j < 2; ++j) {
                    if (val[j]) {
                        float v = acc[i][j][reg] * rcol[j];
                        if (ncol[j] == lm) ll[m] = v;
                        s += __expf(v - C_SCALE);
                    }
                }
                #pragma unroll
                for (int off = 1; off < 32; off <<= 1) s += __shfl_xor(s, off);
                if (l32 == 0) psum[(size_t)m * NPART + pidx] = s;
            }
        }
    } else {
        // ---- sim epilogue: masked softplus sum ----
        int ln[2];
        #pragma unroll
        for (int j = 0; j < 2; ++j) ln[j] = labels[n0 + wn*64 + j*32 + l32];
        float tot = 0.f;
        #pragma unroll
        for (int i = 0; i < 2; ++i) {
            #pragma unroll
            for (int reg = 0; reg < 16; ++reg) {
                int m = m0 + wm*64 + i*32 + (reg & 3) + 8*(reg >> 2) + 4*kh;
                int lm = labels[m];
                #pragma unroll
                for (int j = 0; j < 2; ++j) {
                    float s = acc[i][j][reg] * SIMSCL;
                    float arg = (lm == ln[j]) ? (-C_SPOS * (s - C_ALPHA))
                                              : ( C_SNEG * (s - C_BETA));
                    tot += softplusf(arg);
                }
            }
        }
        #pragma unroll
        for (int off = 1; off < 64; off <<= 1) tot += __shfl_xor(tot, off);
        if (lane == 0) atomicAdd(align_sum, tot);
    }
}

// ---------------- merge psum partials -> CE sum; last block writes out ----------------
// R3-proven: 256 blocks x 8 rows, ONE same-address atomicAdd per block.
// (2048 serialized same-address atomics in the old version cost ~80 µs.)
__global__ __launch_bounds__(256) void k_merge(const float* __restrict__ psum,
                                               const float* __restrict__ ll,
                                               float* __restrict__ inst_sum,
                                               const float* __restrict__ align_sum,
                                               int* __restrict__ fin,
                                               float* __restrict__ out) {
    const int t = threadIdx.x;
    const int g = t >> 5, l = t & 31;             // 8 groups of 32 lanes
    const int r = blockIdx.x * ROWS_PER_MB + g;
    const float* pr = psum + (size_t)r * NPART;
    float s = 0.f;
    for (int p = l; p < NPART; p += 32) s += pr[p];
    #pragma unroll
    for (int off = 1; off < 32; off <<= 1) s += __shfl_xor(s, off);
    __shared__ float sb[ROWS_PER_MB];
    if (l == 0) sb[g] = C_SCALE + logf(s) - ll[r];
    __syncthreads();
    if (t == 0) {
        float ce = 0.f;
        #pragma unroll
        for (int i = 0; i < ROWS_PER_MB; ++i) ce += sb[i];
        atomicAdd(inst_sum, ce);
        __threadfence();
        if (atomicAdd(fin, 1) == MERGE_BLOCKS - 1) {    // last merge block
            __threadfence();
            float is = atomicAdd(inst_sum, 0.f);        // atomic read, device scope
            float as = atomicAdd((float*)align_sum, 0.f);
            out[0] = is / (float)BATCH;
            out[1] = as * 2.f / (float)BATCH;
        }
    }
}

extern "C" void kernel_launch(void* const* d_in, const int* in_sizes, int n_in,
                              void* d_out, int out_size, void* d_ws, size_t ws_size,
                              hipStream_t stream) {
    const float* vis    = (const float*)d_in[0];
    const float* txt    = (const float*)d_in[1];
    const int*   labels = (const int*)  d_in[2];
    const float* W      = (const float*)d_in[3];
    float* out = (float*)d_out;
    char*  ws  = (char*)d_ws;

    float* align_sum = (float*)(ws + O_ALIGN);
    float* inst_sum  = (float*)(ws + O_INST);
    int*   fin       = (int*)  (ws + O_FIN);
    float* colsq     = (float*)(ws + O_COLSQ);
    u8* Xn = (u8*)(ws + O_XN);
    u8* WT = (u8*)(ws + O_WT);
    float* psum = (float*)(ws + O_PSUM);
    float* ll   = (float*)(ws + O_LL);

    hipMemsetAsync(ws, 0, O_XN, stream);  // zero align/inst/fin/colsq

    k_prep <<<dim3(PREP_TOTAL), 256, 0, stream>>>(vis, txt, W, Xn, WT, colsq);
    k_gemm <<<dim3(M1 / 128, NT1 + 4), 256, 0, stream>>>(Xn, WT, colsq, labels,
                                                         psum, ll, align_sum);
    k_merge<<<dim3(MERGE_BLOCKS), 256, 0, stream>>>(psum, ll, inst_sum, align_sum,
                                                    fin, out);
}

// Round 6
// 247.635 us; speedup vs baseline: 1.4888x; 1.0458x over previous
//
#include <hip/hip_runtime.h>
#include <hip/hip_bf16.h>
#include <math.h>

// Problem constants
#define BATCH 1024
#define FEAT  2048
#define NCLS  11003
#define NPAD  11008      // 86 * 128
#define NT1   86         // N tiles for gemm1
#define NPART (NT1 * 2)  // psum partials per row (2 waves in N per tile)
#define M1    2048       // stacked [v; t]
#define C_SCALE  28.0f
#define C_ALPHA  0.6f
#define C_BETA   0.4f
#define C_SPOS   10.0f
#define C_SNEG   40.0f
#define XSCALE   16.0f              // Xn pre-scale into e4m3 normal range
#define SCL1     (C_SCALE / XSCALE) // logit = SCL1 * rcol * acc
#define SIMSCL   (1.0f / (XSCALE * XSCALE))
#define SCALE1   0x7F7F7F7F         // packed E8M0 = 1.0 in every byte

typedef float floatx4 __attribute__((ext_vector_type(4)));
typedef float f32x16  __attribute__((ext_vector_type(16)));
typedef int   v8i     __attribute__((ext_vector_type(8)));
typedef unsigned char u8;

// ---- workspace layout (bytes) ----
#define O_ALIGN  ((size_t)0)         // f32 align_sum
#define O_INST   ((size_t)64)        // f32 instance-CE sum
#define O_FIN    ((size_t)128)       // int fin counter (merge blocks)
#define O_COLSQ  ((size_t)256)       // NPAD f32  (ends 44288)
#define O_XN     ((size_t)44288)     // 2048*2048 fp8 (normalized [v;t], x16)
#define O_WT     ((size_t)4238592)   // NPAD*2048 fp8 (W^T, raw values)
#define O_PSUM   ((size_t)26782976)  // 2048*NPART f32
#define O_LL     ((size_t)28192000)  // 2048 f32 label logits
// zeroed prefix: [0, O_XN)

#define PREP_WBLOCKS (43 * 32)       // 1376: 256-class x 64-feature tiles
#define PREP_TOTAL   (PREP_WBLOCKS + M1)

#define MERGE_BLOCKS 256
#define ROWS_PER_MB  (M1 / MERGE_BLOCKS)  // 8

__device__ inline float softplusf(float x) {
    return (x > 20.f) ? x : log1pf(expf(x));
}

// async 16B global -> LDS (wave-uniform base + lane*16; layout is lane-linear)
__device__ inline void gll16(const void* g, void* l) {
    __builtin_amdgcn_global_load_lds(
        (const __attribute__((address_space(1))) unsigned int*)g,
        (__attribute__((address_space(3))) unsigned int*)l, 16, 0, 0);
}

__device__ inline unsigned int pack4_fp8(float a, float b, float c, float d) {
    unsigned int p = __builtin_amdgcn_cvt_pk_fp8_f32(a, b, 0, false);
    p = __builtin_amdgcn_cvt_pk_fp8_f32(c, d, p, true);
    return p;  // bytes: a,b,c,d
}

// XOR swizzle on 16B-chunk index (self-inverse). R5 LESSON: swz does NOT
// distribute over addition in the chunk-within-row bits (the XOR mask is
// row-dependent; adding a delta to a swizzled address carries out of the
// 3-bit field and lands in the wrong row). ALWAYS apply swz to the COMPLETE
// logical chunk index; never fold deltas onto a swizzled base.
__device__ inline int swz(int c) { return c ^ ((c >> 4) & 7); }

// ---------------- fused prep (unchanged) ----------------
__global__ __launch_bounds__(256) void k_prep(const float* __restrict__ vis,
                                              const float* __restrict__ txt,
                                              const float* __restrict__ W,
                                              u8* __restrict__ Xn,
                                              u8* __restrict__ WT,
                                              float* __restrict__ colsq) {
    __shared__ u8 tileT[1024 * 16];     // 16 KB: 1024 16B chunks (class x f-quad)
    __shared__ float cps[4][256];
    __shared__ float sb[256];
    int t = threadIdx.x;
    if (blockIdx.x < PREP_WBLOCKS) {
        int c0 = (blockIdx.x % 43) * 256, f0 = (blockIdx.x / 43) * 64;
        int w = t >> 6, l = t & 63;
        int cbase = c0 + 4 * l;              // this thread's 4 classes
        unsigned int chunks[4][4];           // [class j][row-quad q]
        float ssq0 = 0.f, ssq1 = 0.f, ssq2 = 0.f, ssq3 = 0.f;
        #pragma unroll
        for (int q = 0; q < 4; ++q) {
            float4 row[4];
            #pragma unroll
            for (int rr = 0; rr < 4; ++rr) {
                int f = f0 + w * 16 + q * 4 + rr;
                const float* p = W + (size_t)f * NCLS + cbase;
                float4 v;
                if (cbase + 3 < NCLS) {
                    __builtin_memcpy(&v, p, 16);   // HW unaligned global load
                } else {
                    v.x = (cbase + 0 < NCLS) ? p[0] : 0.f;
                    v.y = (cbase + 1 < NCLS) ? p[1] : 0.f;
                    v.z = (cbase + 2 < NCLS) ? p[2] : 0.f;
                    v.w = (cbase + 3 < NCLS) ? p[3] : 0.f;
                }
                row[rr] = v;
            }
            chunks[0][q] = pack4_fp8(row[0].x, row[1].x, row[2].x, row[3].x);
            chunks[1][q] = pack4_fp8(row[0].y, row[1].y, row[2].y, row[3].y);
            chunks[2][q] = pack4_fp8(row[0].z, row[1].z, row[2].z, row[3].z);
            chunks[3][q] = pack4_fp8(row[0].w, row[1].w, row[2].w, row[3].w);
            #pragma unroll
            for (int rr = 0; rr < 4; ++rr) {
                ssq0 += row[rr].x * row[rr].x;
                ssq1 += row[rr].y * row[rr].y;
                ssq2 += row[rr].z * row[rr].z;
                ssq3 += row[rr].w * row[rr].w;
            }
        }
        #pragma unroll
        for (int j = 0; j < 4; ++j) {
            int L = (4 * l + j) * 4 + w;     // logical chunk: class-local * 4 + f-quad
            int P = L ^ ((L >> 4) & 7);
            *(uint4*)(tileT + P * 16) =
                make_uint4(chunks[j][0], chunks[j][1], chunks[j][2], chunks[j][3]);
        }
        *(float4*)&cps[w][4 * l] = make_float4(ssq0, ssq1, ssq2, ssq3);
        __syncthreads();
        int c = c0 + t;
        uint4 och[4];
        #pragma unroll
        for (int w2 = 0; w2 < 4; ++w2) {
            int L = t * 4 + w2;
            int P = L ^ ((L >> 4) & 7);
            och[w2] = *(const uint4*)(tileT + P * 16);
        }
        uint4* dst = (uint4*)(WT + (size_t)c * FEAT + f0);
        dst[0] = och[0]; dst[1] = och[1]; dst[2] = och[2]; dst[3] = och[3];
        float s = cps[0][t] + cps[1][t] + cps[2][t] + cps[3][t];
        if (c < NCLS) atomicAdd(&colsq[c], s);
    } else {
        int r = blockIdx.x - PREP_WBLOCKS;
        const float* src = (r < BATCH) ? (vis + (size_t)r * FEAT)
                                       : (txt + (size_t)(r - BATCH) * FEAT);
        float4 x0 = ((const float4*)src)[t];
        float4 x1 = ((const float4*)src)[t + 256];
        float ss = x0.x*x0.x + x0.y*x0.y + x0.z*x0.z + x0.w*x0.w
                 + x1.x*x1.x + x1.y*x1.y + x1.z*x1.z + x1.w*x1.w;
        sb[t] = ss; __syncthreads();
        for (int s = 128; s > 0; s >>= 1) { if (t < s) sb[t] += sb[t + s]; __syncthreads(); }
        float rn = rsqrtf(sb[0]) * XSCALE;
        unsigned int* dst = (unsigned int*)(Xn + (size_t)r * FEAT);
        dst[t]       = pack4_fp8(x0.x*rn, x0.y*rn, x0.z*rn, x0.w*rn);
        dst[t + 256] = pack4_fp8(x1.x*rn, x1.y*rn, x1.z*rn, x1.w*rn);
    }
}

// ---------------- fused GEMM: lse tiles (y<86) + sim tiles (y>=86) ----------------
// R6: BK=128 (R5 theory) with the swizzle-fold bug FIXED: all 16 read
// pointers are computed with swz() applied to the COMPLETE logical chunk
// index (R0's proven pattern), not a swizzled base + delta.
// 16 K-steps x 8 MFMA; 8 gll16 in flight per thread per step.
// HISTORY — do not retry:
//  * R1/R2: explicit LDS dbuf + raw s_barrier + vmcnt(0) -> 2x SLOWER.
//  * R3: XCD-chunked work swizzle -> FETCH halved but 2.2x SLOWER.
//  * R5: folding ks/cc deltas onto swizzled base -> WRONG ROW reads, NaN.
// Wave tile 64x64 = 2x2 of 32x32. A frag: row=lane&31, K-half=lane>>5, 32 bytes.
// C/D: col=lane&31, row=(reg&3)+8*(reg>>2)+4*(lane>>5).
// LDS tile layout: logical chunk = row*8 + h (h = 16B chunk within 128B row),
// stored at LDS chunk swz(logical). Fragment for (i, ks): row = wm*64+i*32+l32,
// h = ks*4 + kh*2 + {0,1}.
__global__ __launch_bounds__(256, 3) void k_gemm(const u8* __restrict__ Xn,
                                              const u8* __restrict__ WT,
                                              const float* __restrict__ colsq,
                                              const int* __restrict__ labels,
                                              float* __restrict__ psum,
                                              float* __restrict__ ll,
                                              float* __restrict__ align_sum) {
    __shared__ u8 As[128 * 128], Bs[128 * 128];   // 16 KB + 16 KB
    f32x16 acc[2][2] = {};
    const int t = threadIdx.x;
    const bool is_sim = (blockIdx.y >= NT1);
    int m0, n0;
    const u8 *A, *B;
    if (!is_sim) {
        m0 = blockIdx.x * 128; n0 = blockIdx.y * 128;
        A = Xn; B = WT;
    } else {
        int s = (blockIdx.y - NT1) * 16 + blockIdx.x;   // 0..63
        m0 = (s >> 3) * 128; n0 = (s & 7) * 128;
        A = Xn; B = Xn + (size_t)BATCH * FEAT;
    }
    // staging: thread t owns LDS chunks {t, 256+t, 512+t, 768+t} (lane-linear
    // per gll16 requirement); global source is the inverse-swizzled chunk.
    const u8 *Ag[4], *Bg[4];
    u8 *lA[4], *lB[4];
    #pragma unroll
    for (int q = 0; q < 4; ++q) {
        int P = q * 256 + t;
        int L = swz(P);
        int r = L >> 3, h = L & 7;
        Ag[q] = A + (size_t)(m0 + r) * FEAT + h * 16;
        Bg[q] = B + (size_t)(n0 + r) * FEAT + h * 16;
        lA[q] = As + P * 16;
        lB[q] = Bs + P * 16;
    }

    const int wave = t >> 6, lane = t & 63;
    const int wm = wave >> 1, wn = wave & 1;
    const int l32 = lane & 31, kh = lane >> 5;
    // 16 fully-swizzled read pointers: [i][ks][cc]
    const uint4* Ard[2][2][2]; const uint4* Brd[2][2][2];
    #pragma unroll
    for (int i = 0; i < 2; ++i)
        #pragma unroll
        for (int ks = 0; ks < 2; ++ks)
            #pragma unroll
            for (int cc = 0; cc < 2; ++cc) {
                int ca = (wm*64 + i*32 + l32) * 8 + ks*4 + kh*2 + cc;
                int cb = (wn*64 + i*32 + l32) * 8 + ks*4 + kh*2 + cc;
                Ard[i][ks][cc] = (const uint4*)(As + swz(ca) * 16);
                Brd[i][ks][cc] = (const uint4*)(Bs + swz(cb) * 16);
            }

    for (int kt = 0; kt < FEAT / 128; ++kt) {
        __syncthreads();
        #pragma unroll
        for (int q = 0; q < 4; ++q) {
            gll16(Ag[q], lA[q]);
            gll16(Bg[q], lB[q]);
        }
        #pragma unroll
        for (int q = 0; q < 4; ++q) { Ag[q] += 128; Bg[q] += 128; }
        __syncthreads();
        #pragma unroll
        for (int ks = 0; ks < 2; ++ks) {
            v8i a[2], b[2];
            #pragma unroll
            for (int i = 0; i < 2; ++i) {
                ((uint4*)&a[i])[0] = *Ard[i][ks][0];
                ((uint4*)&a[i])[1] = *Ard[i][ks][1];
                ((uint4*)&b[i])[0] = *Brd[i][ks][0];
                ((uint4*)&b[i])[1] = *Brd[i][ks][1];
            }
            #pragma unroll
            for (int i = 0; i < 2; ++i)
                #pragma unroll
                for (int j = 0; j < 2; ++j)
                    acc[i][j] = __builtin_amdgcn_mfma_scale_f32_32x32x64_f8f6f4(
                        a[i], b[j], acc[i][j], 0, 0, 0, SCALE1, 0, SCALE1);
        }
    }

    if (!is_sim) {
        // ---- LSE epilogue: fixed-max sum of exp(logit - 28) + label-logit scatter ----
        float rcol[2]; bool val[2]; int ncol[2];
        #pragma unroll
        for (int j = 0; j < 2; ++j) {
            ncol[j] = n0 + wn*64 + j*32 + l32;
            val[j] = (ncol[j] < NCLS);
            rcol[j] = val[j] ? (SCL1 * rsqrtf(colsq[ncol[j]])) : 0.f;
        }
        const int pidx = blockIdx.y * 2 + wn;
        #pragma unroll
        for (int i = 0; i < 2; ++i) {
            #pragma unroll
            for (int reg = 0; reg < 16; ++reg) {
                int m = m0 + wm*64 + i*32 + (reg & 3) + 8*(reg >> 2) + 4*kh;
                int lm = labels[m & (BATCH - 1)];
                float s = 0.f;
                #pragma unroll
                for (int j = 0; j < 2; ++j) {
                    if (val[j]) {
                        float v = acc[i][j][reg] * rcol[j];
                        if (ncol[j] == lm) ll[m] = v;
                        s += __expf(v - C_SCALE);
                    }
                }
                #pragma unroll
                for (int off = 1; off < 32; off <<= 1) s += __shfl_xor(s, off);
                if (l32 == 0) psum[(size_t)m * NPART + pidx] = s;
            }
        }
    } else {
        // ---- sim epilogue: masked softplus sum ----
        int ln[2];
        #pragma unroll
        for (int j = 0; j < 2; ++j) ln[j] = labels[n0 + wn*64 + j*32 + l32];
        float tot = 0.f;
        #pragma unroll
        for (int i = 0; i < 2; ++i) {
            #pragma unroll
            for (int reg = 0; reg < 16; ++reg) {
                int m = m0 + wm*64 + i*32 + (reg & 3) + 8*(reg >> 2) + 4*kh;
                int lm = labels[m];
                #pragma unroll
                for (int j = 0; j < 2; ++j) {
                    float s = acc[i][j][reg] * SIMSCL;
                    float arg = (lm == ln[j]) ? (-C_SPOS * (s - C_ALPHA))
                                              : ( C_SNEG * (s - C_BETA));
                    tot += softplusf(arg);
                }
            }
        }
        #pragma unroll
        for (int off = 1; off < 64; off <<= 1) tot += __shfl_xor(tot, off);
        if (lane == 0) atomicAdd(align_sum, tot);
    }
}

// ---------------- merge psum partials -> CE sum; last block writes out ----------------
// R3-proven: 256 blocks x 8 rows, ONE same-address atomicAdd per block.
__global__ __launch_bounds__(256) void k_merge(const float* __restrict__ psum,
                                               const float* __restrict__ ll,
                                               float* __restrict__ inst_sum,
                                               const float* __restrict__ align_sum,
                                               int* __restrict__ fin,
                                               float* __restrict__ out) {
    const int t = threadIdx.x;
    const int g = t >> 5, l = t & 31;             // 8 groups of 32 lanes
    const int r = blockIdx.x * ROWS_PER_MB + g;
    const float* pr = psum + (size_t)r * NPART;
    float s = 0.f;
    for (int p = l; p < NPART; p += 32) s += pr[p];
    #pragma unroll
    for (int off = 1; off < 32; off <<= 1) s += __shfl_xor(s, off);
    __shared__ float sb[ROWS_PER_MB];
    if (l == 0) sb[g] = C_SCALE + logf(s) - ll[r];
    __syncthreads();
    if (t == 0) {
        float ce = 0.f;
        #pragma unroll
        for (int i = 0; i < ROWS_PER_MB; ++i) ce += sb[i];
        atomicAdd(inst_sum, ce);
        __threadfence();
        if (atomicAdd(fin, 1) == MERGE_BLOCKS - 1) {    // last merge block
            __threadfence();
            float is = atomicAdd(inst_sum, 0.f);        // atomic read, device scope
            float as = atomicAdd((float*)align_sum, 0.f);
            out[0] = is / (float)BATCH;
            out[1] = as * 2.f / (float)BATCH;
        }
    }
}

extern "C" void kernel_launch(void* const* d_in, const int* in_sizes, int n_in,
                              void* d_out, int out_size, void* d_ws, size_t ws_size,
                              hipStream_t stream) {
    const float* vis    = (const float*)d_in[0];
    const float* txt    = (const float*)d_in[1];
    const int*   labels = (const int*)  d_in[2];
    const float* W      = (const float*)d_in[3];
    float* out = (float*)d_out;
    char*  ws  = (char*)d_ws;

    float* align_sum = (float*)(ws + O_ALIGN);
    float* inst_sum  = (float*)(ws + O_INST);
    int*   fin       = (int*)  (ws + O_FIN);
    float* colsq     = (float*)(ws + O_COLSQ);
    u8* Xn = (u8*)(ws + O_XN);
    u8* WT = (u8*)(ws + O_WT);
    float* psum = (float*)(ws + O_PSUM);
    float* ll   = (float*)(ws + O_LL);

    hipMemsetAsync(ws, 0, O_XN, stream);  // zero align/inst/fin/colsq

    k_prep <<<dim3(PREP_TOTAL), 256, 0, stream>>>(vis, txt, W, Xn, WT, colsq);
    k_gemm <<<dim3(M1 / 128, NT1 + 4), 256, 0, stream>>>(Xn, WT, colsq, labels,
                                                         psum, ll, align_sum);
    k_merge<<<dim3(MERGE_BLOCKS), 256, 0, stream>>>(psum, ll, inst_sum, align_sum,
                                                    fin, out);
}